// Round 3
// baseline (251.990 us; speedup 1.0000x reference)
//
#include <hip/hip_runtime.h>
#include <math.h>

#define BB 8
#define TT 4096
#define FF 1024
#define F4 (FF / 4)        // 256 float4 per row
#define TS 256             // t-chunks per batch (finer for tail balance)
#define TCHUNK (TT / TS)   // 16 timesteps per chunk

typedef float vfloat4 __attribute__((ext_vector_type(4)));

// ---------------------------------------------------------------------------
// Kernel 1: partial masked column sums, valid-prefix skip, no LDS/barrier.
// mask chunk read as 4x int4 broadcast loads; prefix => nv = popcount.
// grid: (TS, BB) = 2048 blocks (8/CU), block: 256.
// ---------------------------------------------------------------------------
__global__ __launch_bounds__(256) void k1_partial(const float4* __restrict__ x4,
                                                  const int* __restrict__ mask,
                                                  float4* __restrict__ part4,
                                                  float* __restrict__ Sk,
                                                  float* __restrict__ Skk) {
    const int ts  = blockIdx.x;
    const int b   = blockIdx.y;
    const int tid = threadIdx.x;

    if (ts == 0 && tid == 0) { Sk[b] = 0.f; Skk[b] = 0.f; }   // ws is poisoned

    const int4* mrow = (const int4*)(mask + (size_t)b * TT + ts * TCHUNK);
    int4 m0 = mrow[0], m1 = mrow[1], m2 = mrow[2], m3 = mrow[3];  // broadcast
    const int nv = m0.x + m0.y + m0.z + m0.w + m1.x + m1.y + m1.z + m1.w
                 + m2.x + m2.y + m2.z + m2.w + m3.x + m3.y + m3.z + m3.w;
    if (nv == 0) return;                      // dead chunk: no reads, no store

    const float4* xb = x4 + ((size_t)b * TT + (size_t)ts * TCHUNK) * F4 + tid;
    float4 acc = make_float4(0.f, 0.f, 0.f, 0.f);
    #pragma unroll 8
    for (int t = 0; t < nv; ++t) {            // prefix => plain adds
        float4 v = xb[(size_t)t * F4];
        acc.x += v.x; acc.y += v.y; acc.z += v.z; acc.w += v.w;
    }
    part4[((size_t)b * TS + ts) * F4 + tid] = acc;
}

// ---------------------------------------------------------------------------
// Kernel 2: k[b,f] = colsum/L, plus Sk[b]=sum(k), Skk[b]=sum(k^2) via atomics.
// 256 blocks (32 per batch x 32-channel groups); reads only nts written
// chunks. grid: 256, block: 256.
// ---------------------------------------------------------------------------
__global__ __launch_bounds__(256) void k2_stats(const float* __restrict__ part,
                                                const int* __restrict__ mask,
                                                float* __restrict__ kbuf,
                                                float* __restrict__ Sk,
                                                float* __restrict__ Skk) {
    __shared__ float red[8][32];
    __shared__ float Lred[4];

    const int tid   = threadIdx.x;
    const int wave  = tid >> 6;
    const int lane  = tid & 63;
    const int b2    = blockIdx.x >> 5;
    const int fbase = (blockIdx.x & 31) * 32;

    // ---- valid length L (mask is cache-hot after k1) ----
    int c = 0;
    #pragma unroll
    for (int i = 0; i < 16; ++i) c += mask[(size_t)b2 * TT + tid + 256 * i];
    float fc = (float)c;
    #pragma unroll
    for (int off = 32; off; off >>= 1) fc += __shfl_xor(fc, off);
    if (lane == 0) Lred[wave] = fc;
    __syncthreads();
    const float Lf  = Lred[0] + Lred[1] + Lred[2] + Lred[3];
    const int   nts = ((int)Lf + TCHUNK - 1) / TCHUNK;   // only these written

    // ---- column sums: 8 ts-slices per channel ----
    const int f     = fbase + (tid & 31);
    const int slice = tid >> 5;
    float s = 0.f;
    for (int t = slice; t < nts; t += 8)
        s += part[((size_t)b2 * TS + t) * FF + f];
    red[slice][tid & 31] = s;
    __syncthreads();

    if (tid < 32) {
        float sum = 0.f;
        #pragma unroll
        for (int sl = 0; sl < 8; ++sl) sum += red[sl][tid];
        const float kv = sum / Lf;
        kbuf[(size_t)b2 * FF + fbase + tid] = kv;
        float a = kv, q = kv * kv;
        #pragma unroll
        for (int off = 16; off; off >>= 1) {
            a += __shfl_xor(a, off);
            q += __shfl_xor(q, off);
        }
        if (tid == 0) {
            atomicAdd(&Sk[b2],  a);
            atomicAdd(&Skk[b2], q);
        }
    }
}

// ---------------------------------------------------------------------------
// Kernel 3: gate + apply, 4 rows per wave (16 per block). k row hoisted to
// registers ONCE per wave and reused 4x (cuts redundant k L2 traffic 4x);
// mask as one broadcast int4 (prefix => nv); x loads software-pipelined
// across rows to overlap the per-row latency chain. Nontemporal stores.
// grid: (TT/16, BB) = 2048 blocks, block: 256.
// ---------------------------------------------------------------------------
__global__ __launch_bounds__(256) void k3_apply(const float4* __restrict__ x4,
                                                const int* __restrict__ mask,
                                                const float4* __restrict__ kb4,
                                                const float* __restrict__ Sk,
                                                const float* __restrict__ Skk,
                                                float4* __restrict__ out4) {
    const int wave = threadIdx.x >> 6;
    const int lane = threadIdx.x & 63;
    const int b    = blockIdx.y;
    const int rowbase = blockIdx.x * 16 + wave * 4;      // 4 rows per wave
    const size_t base = ((size_t)b * TT + rowbase) * F4;

    // mask for my 4 rows: one 16B broadcast load; prefix => count = boundary
    const int4 m4 = *(const int4*)(mask + (size_t)b * TT + rowbase);
    const int  nv = m4.x + m4.y + m4.z + m4.w;

    // zero-store padded rows first (no data deps)
    for (int i = nv; i < 4; ++i) {
        vfloat4* orow = (vfloat4*)(out4 + base + (size_t)i * F4);
        vfloat4 z = (vfloat4)(0.f);
        #pragma unroll
        for (int j = 0; j < 4; ++j)
            __builtin_nontemporal_store(z, orow + lane + 64 * j);
    }
    if (nv == 0) return;

    // k row: load once, reuse for all 4 rows
    const float4* krow = kb4 + (size_t)b * F4;
    float4 kv[4];
    #pragma unroll
    for (int j = 0; j < 4; ++j) kv[j] = krow[lane + 64 * j];

    const float sk  = Sk[b];
    const float kd  = sqrtf(fmaxf(Skk[b] - sk * sk * (1.0f / FF), 0.f));

    // software pipeline: prefetch row i+1 while reducing row i
    float4 xn[4];
    #pragma unroll
    for (int j = 0; j < 4; ++j) xn[j] = (x4 + base)[lane + 64 * j];

    for (int i = 0; i < nv; ++i) {
        float4 xv[4];
        #pragma unroll
        for (int j = 0; j < 4; ++j) xv[j] = xn[j];
        if (i + 1 < nv) {
            const float4* xrow = x4 + base + (size_t)(i + 1) * F4;
            #pragma unroll
            for (int j = 0; j < 4; ++j) xn[j] = xrow[lane + 64 * j];
        }

        float s1 = 0.f, s2 = 0.f, s3 = 0.f;
        #pragma unroll
        for (int j = 0; j < 4; ++j) {
            s1 += xv[j].x + xv[j].y + xv[j].z + xv[j].w;
            s2 = fmaf(xv[j].x, xv[j].x, fmaf(xv[j].y, xv[j].y,
                 fmaf(xv[j].z, xv[j].z, fmaf(xv[j].w, xv[j].w, s2))));
            s3 = fmaf(xv[j].x, kv[j].x, fmaf(xv[j].y, kv[j].y,
                 fmaf(xv[j].z, kv[j].z, fmaf(xv[j].w, kv[j].w, s3))));
        }
        #pragma unroll
        for (int off = 32; off; off >>= 1) {
            s1 += __shfl_xor(s1, off);
            s2 += __shfl_xor(s2, off);
            s3 += __shfl_xor(s3, off);
        }

        const float mx  = s1 * (1.0f / FF);
        const float num = s3 - mx * sk;                       // dot(x_c, k_c)
        const float qd  = sqrtf(fmaxf(s2 - s1 * s1 * (1.0f / FF), 0.f));
        const float C   = num / (qd * kd);
        const float A   = 1.0f / (1.0f + __expf(C));          // 1 - sigmoid

        vfloat4* orow = (vfloat4*)(out4 + base + (size_t)i * F4);
        #pragma unroll
        for (int j = 0; j < 4; ++j) {
            vfloat4 o;
            o.x = xv[j].x * A; o.y = xv[j].y * A;
            o.z = xv[j].z * A; o.w = xv[j].w * A;
            __builtin_nontemporal_store(o, orow + lane + 64 * j);
        }
    }
}

// ---------------------------------------------------------------------------
extern "C" void kernel_launch(void* const* d_in, const int* in_sizes, int n_in,
                              void* d_out, int out_size, void* d_ws, size_t ws_size,
                              hipStream_t stream) {
    const float* x    = (const float*)d_in[0];
    const int*   mask = (const int*)d_in[1];
    float*       out  = (float*)d_out;

    // workspace (floats): part[B*TS*F] | kbuf[B*F] | Sk[B] | Skk[B]
    float* part = (float*)d_ws;
    float* kbuf = part + (size_t)BB * TS * FF;
    float* Sk   = kbuf + (size_t)BB * FF;
    float* Skk  = Sk + BB;

    k1_partial<<<dim3(TS, BB), 256, 0, stream>>>((const float4*)x, mask,
                                                 (float4*)part, Sk, Skk);
    k2_stats<<<256, 256, 0, stream>>>(part, mask, kbuf, Sk, Skk);
    k3_apply<<<dim3(TT / 16, BB), 256, 0, stream>>>((const float4*)x, mask,
                                                    (const float4*)kbuf, Sk, Skk,
                                                    (float4*)out);
}